// Round 3
// baseline (307.991 us; speedup 1.0000x reference)
//
#include <hip/hip_runtime.h>

// NeighbourCovariance: V=200000, C=3, F=16, K=32
// out[v] = [cov_flat (F*6=96), mean_flat (F*3=48)] -> 144 f32 per vertex.

#define EPS 1e-6f

constexpr int C_DIM = 3;
constexpr int F_DIM = 16;
constexpr int K_N = 32;
constexpr int V_PER_BLOCK = 64;   // 256 threads, 4 threads/vertex
constexpr int THREADS = 256;

// Native clang vector type — __builtin_nontemporal_* accepts these
// (it rejects HIP_vector_type wrappers like float4).
typedef float v4f __attribute__((ext_vector_type(4)));

// ---------------------------------------------------------------------------
// Prepass: pack coords [V,3] -> ws [V] float4 (x,y,z,0). One 16B record per
// vertex so the main loop's coord read is a single dwordx4 broadcast instead
// of 3 scalar dword gathers.
// ---------------------------------------------------------------------------
__global__ __launch_bounds__(256) void pack_coords_kernel(
    const float* __restrict__ coords, v4f* __restrict__ cpack, int V)
{
  int v = blockIdx.x * blockDim.x + threadIdx.x;
  if (v >= V) return;
  v4f r;
  r.x = coords[(size_t)v * 3 + 0];
  r.y = coords[(size_t)v * 3 + 1];
  r.z = coords[(size_t)v * 3 + 2];
  r.w = 0.f;
  cpack[v] = r;
}

// ---------------------------------------------------------------------------
// Main kernel. PACKED selects the float4-coord path (workspace available).
// ---------------------------------------------------------------------------
template <bool PACKED>
__global__ __launch_bounds__(THREADS) void neigh_cov_kernel(
    const float* __restrict__ coords,   // [V,3]
    const v4f*   __restrict__ cpack,    // [V] packed coords (if PACKED)
    const float* __restrict__ feats,    // [V,16]
    const int*   __restrict__ nidx,     // [V,32]
    float*       __restrict__ out,      // [V,144]
    int V)
{
  // Stage this block's neighbor indices in LDS (stride 33 kills the 16-way
  // bank conflict a stride-32 layout would have at fixed k).
  __shared__ int sidx[V_PER_BLOCK][K_N + 1];

  const int tid = threadIdx.x;
  const int block_v0 = blockIdx.x * V_PER_BLOCK;

  {
    const long long base = (long long)block_v0 * K_N;
    const long long avail = (long long)V * K_N - base;
    #pragma unroll
    for (int i = tid; i < V_PER_BLOCK * K_N; i += THREADS) {
      // Index stream is read exactly once -> nontemporal, don't pollute L2.
      int val = (i < avail) ? __builtin_nontemporal_load(nidx + base + i) : 0;
      sidx[i / K_N][i % K_N] = val;
    }
  }
  __syncthreads();

  const int vloc = tid >> 2;   // vertex within block
  const int t    = tid & 3;    // feature quad: features 4t..4t+3
  const int v    = block_v0 + vloc;
  if (v >= V) return;

  float s[4]   = {0.f, 0.f, 0.f, 0.f};
  float wx0[4] = {0.f, 0.f, 0.f, 0.f};
  float wx1[4] = {0.f, 0.f, 0.f, 0.f};
  float wx2[4] = {0.f, 0.f, 0.f, 0.f};
  float e00[4] = {0.f, 0.f, 0.f, 0.f};
  float e10[4] = {0.f, 0.f, 0.f, 0.f};
  float e11[4] = {0.f, 0.f, 0.f, 0.f};
  float e20[4] = {0.f, 0.f, 0.f, 0.f};
  float e21[4] = {0.f, 0.f, 0.f, 0.f};
  float e22[4] = {0.f, 0.f, 0.f, 0.f};

  #pragma unroll 8
  for (int k = 0; k < K_N; ++k) {
    const int idx = sidx[vloc][k];
    // Feature quad: 16B/lane, the 4 lanes of a vertex cover one 64B segment.
    const v4f w4 = *reinterpret_cast<const v4f*>(
        feats + (size_t)idx * F_DIM + t * 4);

    float x0, x1, x2;
    if (PACKED) {
      const v4f cc = cpack[idx];   // one 16B broadcast request per vertex
      x0 = cc.x; x1 = cc.y; x2 = cc.z;
    } else {
      x0 = coords[(size_t)idx * C_DIM + 0];
      x1 = coords[(size_t)idx * C_DIM + 1];
      x2 = coords[(size_t)idx * C_DIM + 2];
    }

    const float xx00 = x0 * x0;
    const float xx10 = x1 * x0;
    const float xx11 = x1 * x1;
    const float xx20 = x2 * x0;
    const float xx21 = x2 * x1;
    const float xx22 = x2 * x2;

    const float wv[4] = {w4.x, w4.y, w4.z, w4.w};
    #pragma unroll
    for (int j = 0; j < 4; ++j) {
      const float w = wv[j];
      s[j]   += w;
      wx0[j] = fmaf(w, x0, wx0[j]);
      wx1[j] = fmaf(w, x1, wx1[j]);
      wx2[j] = fmaf(w, x2, wx2[j]);
      e00[j] = fmaf(w, xx00, e00[j]);
      e10[j] = fmaf(w, xx10, e10[j]);
      e11[j] = fmaf(w, xx11, e11[j]);
      e20[j] = fmaf(w, xx20, e20[j]);
      e21[j] = fmaf(w, xx21, e21[j]);
      e22[j] = fmaf(w, xx22, e22[j]);
    }
  }

  // Epilogue: cov lower-tri order (0,0),(1,0),(1,1),(2,0),(2,1),(2,2) + mean.
  float cov[24];
  float mn[12];
  #pragma unroll
  for (int j = 0; j < 4; ++j) {
    const float iw = 1.0f / (s[j] + EPS);
    const float m0 = wx0[j] * iw;
    const float m1 = wx1[j] * iw;
    const float m2 = wx2[j] * iw;
    cov[j * 6 + 0] = fmaf(-m0, m0, e00[j] * iw);
    cov[j * 6 + 1] = fmaf(-m1, m0, e10[j] * iw);
    cov[j * 6 + 2] = fmaf(-m1, m1, e11[j] * iw);
    cov[j * 6 + 3] = fmaf(-m2, m0, e20[j] * iw);
    cov[j * 6 + 4] = fmaf(-m2, m1, e21[j] * iw);
    cov[j * 6 + 5] = fmaf(-m2, m2, e22[j] * iw);
    mn[j * 3 + 0] = m0;
    mn[j * 3 + 1] = m1;
    mn[j * 3 + 2] = m2;
  }

  // Output written once, never read again -> nontemporal 16B stores
  // (don't evict the hot feature array from L2). All offsets 16B-aligned.
  float* outv = out + (size_t)v * 144;
  v4f* cdst = reinterpret_cast<v4f*>(outv + t * 24);       // 24 floats
  const v4f* csrc = reinterpret_cast<const v4f*>(cov);
  #pragma unroll
  for (int q = 0; q < 6; ++q) __builtin_nontemporal_store(csrc[q], cdst + q);
  v4f* mdst = reinterpret_cast<v4f*>(outv + 96 + t * 12);  // 12 floats
  const v4f* msrc = reinterpret_cast<const v4f*>(mn);
  #pragma unroll
  for (int q = 0; q < 3; ++q) __builtin_nontemporal_store(msrc[q], mdst + q);
}

extern "C" void kernel_launch(void* const* d_in, const int* in_sizes, int n_in,
                              void* d_out, int out_size, void* d_ws, size_t ws_size,
                              hipStream_t stream) {
  const float* coords = (const float*)d_in[0];
  const float* feats  = (const float*)d_in[1];
  const int*   nidx   = (const int*)d_in[2];
  float* out = (float*)d_out;

  const int V = in_sizes[0] / C_DIM;   // 200000
  const int blocks = (V + V_PER_BLOCK - 1) / V_PER_BLOCK;

  const size_t packed_bytes = (size_t)V * sizeof(v4f);
  const bool use_packed = (d_ws != nullptr) && (ws_size >= packed_bytes);

  if (use_packed) {
    v4f* cpack = (v4f*)d_ws;
    pack_coords_kernel<<<(V + 255) / 256, 256, 0, stream>>>(coords, cpack, V);
    neigh_cov_kernel<true><<<blocks, THREADS, 0, stream>>>(
        coords, cpack, feats, nidx, out, V);
  } else {
    neigh_cov_kernel<false><<<blocks, THREADS, 0, stream>>>(
        coords, nullptr, feats, nidx, out, V);
  }
}

// Round 4
// 179.823 us; speedup vs baseline: 1.7127x; 1.7127x over previous
//
#include <hip/hip_runtime.h>

// NeighbourCovariance: V=200000, C=3, F=16, K=32
// out[v] = [cov_flat (F*6=96), mean_flat (F*3=48)] -> 144 f32 per vertex.

#define EPS 1e-6f

constexpr int C_DIM = 3;
constexpr int F_DIM = 16;
constexpr int K_N = 32;
constexpr int V_PER_BLOCK = 64;   // 256 threads, 4 threads/vertex
constexpr int THREADS = 256;

typedef float v4f __attribute__((ext_vector_type(4)));

// ---------------------------------------------------------------------------
// Prepass: pack coords [V,3] -> ws [V] float4 (x,y,z,0). One 16B record per
// vertex so the main loop's coord read is a single dwordx4 broadcast instead
// of 3 scalar dword gathers.
// ---------------------------------------------------------------------------
__global__ __launch_bounds__(256) void pack_coords_kernel(
    const float* __restrict__ coords, v4f* __restrict__ cpack, int V)
{
  int v = blockIdx.x * blockDim.x + threadIdx.x;
  if (v >= V) return;
  v4f r;
  r.x = coords[(size_t)v * 3 + 0];
  r.y = coords[(size_t)v * 3 + 1];
  r.z = coords[(size_t)v * 3 + 2];
  r.w = 0.f;
  cpack[v] = r;
}

// ---------------------------------------------------------------------------
// Main kernel. PACKED selects the float4-coord path (workspace available).
// NOTE (R3 post-mortem): do NOT use nontemporal stores for the output —
// bypassing L2 write-combining turned 115 MB of writes into 351 MB of
// partial-line HBM transactions (3x amplification, 167us -> 308us).
// ---------------------------------------------------------------------------
template <bool PACKED>
__global__ __launch_bounds__(THREADS) void neigh_cov_kernel(
    const float* __restrict__ coords,   // [V,3]
    const v4f*   __restrict__ cpack,    // [V] packed coords (if PACKED)
    const float* __restrict__ feats,    // [V,16]
    const int*   __restrict__ nidx,     // [V,32]
    float*       __restrict__ out,      // [V,144]
    int V)
{
  // Stage this block's neighbor indices in LDS (stride 33 kills the 16-way
  // bank conflict a stride-32 layout would have at fixed k).
  __shared__ int sidx[V_PER_BLOCK][K_N + 1];

  const int tid = threadIdx.x;
  const int block_v0 = blockIdx.x * V_PER_BLOCK;

  {
    const long long base = (long long)block_v0 * K_N;
    const long long avail = (long long)V * K_N - base;
    #pragma unroll
    for (int i = tid; i < V_PER_BLOCK * K_N; i += THREADS) {
      // Index stream is read exactly once -> nontemporal load (read hint
      // only; harmless, keeps the once-read stream from displacing L2).
      int val = (i < avail) ? __builtin_nontemporal_load(nidx + base + i) : 0;
      sidx[i / K_N][i % K_N] = val;
    }
  }
  __syncthreads();

  const int vloc = tid >> 2;   // vertex within block
  const int t    = tid & 3;    // feature quad: features 4t..4t+3
  const int v    = block_v0 + vloc;
  if (v >= V) return;

  float s[4]   = {0.f, 0.f, 0.f, 0.f};
  float wx0[4] = {0.f, 0.f, 0.f, 0.f};
  float wx1[4] = {0.f, 0.f, 0.f, 0.f};
  float wx2[4] = {0.f, 0.f, 0.f, 0.f};
  float e00[4] = {0.f, 0.f, 0.f, 0.f};
  float e10[4] = {0.f, 0.f, 0.f, 0.f};
  float e11[4] = {0.f, 0.f, 0.f, 0.f};
  float e20[4] = {0.f, 0.f, 0.f, 0.f};
  float e21[4] = {0.f, 0.f, 0.f, 0.f};
  float e22[4] = {0.f, 0.f, 0.f, 0.f};

  // Software pipeline: issue a batch of gathers, accumulate previous batch.
  #pragma unroll
  for (int kb = 0; kb < K_N; kb += 8) {
    v4f w4[8];
    v4f cc[8];
    #pragma unroll
    for (int u = 0; u < 8; ++u) {
      const int idx = sidx[vloc][kb + u];
      w4[u] = *reinterpret_cast<const v4f*>(feats + (size_t)idx * F_DIM + t * 4);
      if (PACKED) {
        cc[u] = cpack[idx];
      } else {
        cc[u].x = coords[(size_t)idx * C_DIM + 0];
        cc[u].y = coords[(size_t)idx * C_DIM + 1];
        cc[u].z = coords[(size_t)idx * C_DIM + 2];
      }
    }
    #pragma unroll
    for (int u = 0; u < 8; ++u) {
      const float x0 = cc[u].x, x1 = cc[u].y, x2 = cc[u].z;
      const float xx00 = x0 * x0;
      const float xx10 = x1 * x0;
      const float xx11 = x1 * x1;
      const float xx20 = x2 * x0;
      const float xx21 = x2 * x1;
      const float xx22 = x2 * x2;
      const float wv[4] = {w4[u].x, w4[u].y, w4[u].z, w4[u].w};
      #pragma unroll
      for (int j = 0; j < 4; ++j) {
        const float w = wv[j];
        s[j]   += w;
        wx0[j] = fmaf(w, x0, wx0[j]);
        wx1[j] = fmaf(w, x1, wx1[j]);
        wx2[j] = fmaf(w, x2, wx2[j]);
        e00[j] = fmaf(w, xx00, e00[j]);
        e10[j] = fmaf(w, xx10, e10[j]);
        e11[j] = fmaf(w, xx11, e11[j]);
        e20[j] = fmaf(w, xx20, e20[j]);
        e21[j] = fmaf(w, xx21, e21[j]);
        e22[j] = fmaf(w, xx22, e22[j]);
      }
    }
  }

  // Epilogue: cov lower-tri order (0,0),(1,0),(1,1),(2,0),(2,1),(2,2) + mean.
  float cov[24];
  float mn[12];
  #pragma unroll
  for (int j = 0; j < 4; ++j) {
    const float iw = 1.0f / (s[j] + EPS);
    const float m0 = wx0[j] * iw;
    const float m1 = wx1[j] * iw;
    const float m2 = wx2[j] * iw;
    cov[j * 6 + 0] = fmaf(-m0, m0, e00[j] * iw);
    cov[j * 6 + 1] = fmaf(-m1, m0, e10[j] * iw);
    cov[j * 6 + 2] = fmaf(-m1, m1, e11[j] * iw);
    cov[j * 6 + 3] = fmaf(-m2, m0, e20[j] * iw);
    cov[j * 6 + 4] = fmaf(-m2, m1, e21[j] * iw);
    cov[j * 6 + 5] = fmaf(-m2, m2, e22[j] * iw);
    mn[j * 3 + 0] = m0;
    mn[j * 3 + 1] = m1;
    mn[j * 3 + 2] = m2;
  }

  // Normal cached float4 stores — L2 write-combines the 4 lanes' interleaved
  // 576B/vertex into full lines. All offsets 16B-aligned.
  float* outv = out + (size_t)v * 144;
  v4f* cdst = reinterpret_cast<v4f*>(outv + t * 24);       // 24 floats
  const v4f* csrc = reinterpret_cast<const v4f*>(cov);
  #pragma unroll
  for (int q = 0; q < 6; ++q) cdst[q] = csrc[q];
  v4f* mdst = reinterpret_cast<v4f*>(outv + 96 + t * 12);  // 12 floats
  const v4f* msrc = reinterpret_cast<const v4f*>(mn);
  #pragma unroll
  for (int q = 0; q < 3; ++q) mdst[q] = msrc[q];
}

extern "C" void kernel_launch(void* const* d_in, const int* in_sizes, int n_in,
                              void* d_out, int out_size, void* d_ws, size_t ws_size,
                              hipStream_t stream) {
  const float* coords = (const float*)d_in[0];
  const float* feats  = (const float*)d_in[1];
  const int*   nidx   = (const int*)d_in[2];
  float* out = (float*)d_out;

  const int V = in_sizes[0] / C_DIM;   // 200000
  const int blocks = (V + V_PER_BLOCK - 1) / V_PER_BLOCK;

  const size_t packed_bytes = (size_t)V * sizeof(v4f);
  const bool use_packed = (d_ws != nullptr) && (ws_size >= packed_bytes);

  if (use_packed) {
    v4f* cpack = (v4f*)d_ws;
    pack_coords_kernel<<<(V + 255) / 256, 256, 0, stream>>>(coords, cpack, V);
    neigh_cov_kernel<true><<<blocks, THREADS, 0, stream>>>(
        coords, cpack, feats, nidx, out, V);
  } else {
    neigh_cov_kernel<false><<<blocks, THREADS, 0, stream>>>(
        coords, nullptr, feats, nidx, out, V);
  }
}

// Round 5
// 142.361 us; speedup vs baseline: 2.1634x; 1.2631x over previous
//
#include <hip/hip_runtime.h>

// NeighbourCovariance: V=200000, C=3, F=16, K=32
// out[v] = [cov_flat (F*6=96), mean_flat (F*3=48)] -> 144 f32 per vertex.
//
// R4 post-mortem: gather stream (feats, 12.8 MB f32) >> per-XCD L2 (4 MB) ->
// ~2/3 miss rate -> 540 MB FETCH. This round: gather fp16 copies (8 MB hot
// footprint) staged in d_ws by a prepass. NT stores stay banned (R3: 3x
// write amplification).

#define EPS 1e-6f

constexpr int C_DIM = 3;
constexpr int F_DIM = 16;
constexpr int K_N = 32;
constexpr int V_PER_BLOCK = 64;   // 256 threads, 4 threads/vertex
constexpr int THREADS = 256;

typedef float v4f __attribute__((ext_vector_type(4)));
typedef _Float16 h4 __attribute__((ext_vector_type(4)));   // 8B

// ---------------------------------------------------------------------------
// Prepass: feats f32[V,16] -> fp16[V,16] (6.4 MB); coords f32[V,3] ->
// fp16x4 (x,y,z,0) [V] (1.6 MB). One thread per vertex.
// ---------------------------------------------------------------------------
__global__ __launch_bounds__(256) void pack_half_kernel(
    const float* __restrict__ coords,
    const float* __restrict__ feats,
    h4* __restrict__ fh,        // [V*4] quads
    h4* __restrict__ ch,        // [V]
    int V)
{
  int v = blockIdx.x * blockDim.x + threadIdx.x;
  if (v >= V) return;
  #pragma unroll
  for (int q = 0; q < 4; ++q) {
    const v4f f = *reinterpret_cast<const v4f*>(feats + (size_t)v * F_DIM + q * 4);
    h4 o;
    o.x = (_Float16)f.x; o.y = (_Float16)f.y;
    o.z = (_Float16)f.z; o.w = (_Float16)f.w;
    fh[(size_t)v * 4 + q] = o;
  }
  h4 c;
  c.x = (_Float16)coords[(size_t)v * 3 + 0];
  c.y = (_Float16)coords[(size_t)v * 3 + 1];
  c.z = (_Float16)coords[(size_t)v * 3 + 2];
  c.w = (_Float16)0.f;
  ch[v] = c;
}

// ---------------------------------------------------------------------------
// Main kernel (fp16 gather path).
// ---------------------------------------------------------------------------
__global__ __launch_bounds__(THREADS) void neigh_cov_h_kernel(
    const h4* __restrict__ fh,     // [V*4] feature quads (8B each)
    const h4* __restrict__ ch,     // [V] packed coords (8B)
    const int* __restrict__ nidx,  // [V,32]
    float* __restrict__ out,       // [V,144]
    int V)
{
  // Stage this block's neighbor indices in LDS (stride 33: conflict-free).
  __shared__ int sidx[V_PER_BLOCK][K_N + 1];

  const int tid = threadIdx.x;
  const int block_v0 = blockIdx.x * V_PER_BLOCK;

  {
    const long long base = (long long)block_v0 * K_N;
    const long long avail = (long long)V * K_N - base;
    #pragma unroll
    for (int i = tid; i < V_PER_BLOCK * K_N; i += THREADS) {
      int val = (i < avail) ? __builtin_nontemporal_load(nidx + base + i) : 0;
      sidx[i / K_N][i % K_N] = val;
    }
  }
  __syncthreads();

  const int vloc = tid >> 2;   // vertex within block
  const int t    = tid & 3;    // feature quad: features 4t..4t+3
  const int v    = block_v0 + vloc;
  if (v >= V) return;

  float s[4]   = {0.f, 0.f, 0.f, 0.f};
  float wx0[4] = {0.f, 0.f, 0.f, 0.f};
  float wx1[4] = {0.f, 0.f, 0.f, 0.f};
  float wx2[4] = {0.f, 0.f, 0.f, 0.f};
  float e00[4] = {0.f, 0.f, 0.f, 0.f};
  float e10[4] = {0.f, 0.f, 0.f, 0.f};
  float e11[4] = {0.f, 0.f, 0.f, 0.f};
  float e20[4] = {0.f, 0.f, 0.f, 0.f};
  float e21[4] = {0.f, 0.f, 0.f, 0.f};
  float e22[4] = {0.f, 0.f, 0.f, 0.f};

  // Batch gathers (8 in flight x 2 loads of 8B) then accumulate.
  #pragma unroll
  for (int kb = 0; kb < K_N; kb += 8) {
    h4 w4[8];
    h4 cc[8];
    #pragma unroll
    for (int u = 0; u < 8; ++u) {
      const int idx = sidx[vloc][kb + u];
      w4[u] = fh[(size_t)idx * 4 + t];   // 8B, 4 lanes cover a 32B row
      cc[u] = ch[idx];                   // 8B broadcast across the 4 lanes
    }
    #pragma unroll
    for (int u = 0; u < 8; ++u) {
      const float x0 = (float)cc[u].x;
      const float x1 = (float)cc[u].y;
      const float x2 = (float)cc[u].z;
      const float xx00 = x0 * x0;
      const float xx10 = x1 * x0;
      const float xx11 = x1 * x1;
      const float xx20 = x2 * x0;
      const float xx21 = x2 * x1;
      const float xx22 = x2 * x2;
      const float wv[4] = {(float)w4[u].x, (float)w4[u].y,
                           (float)w4[u].z, (float)w4[u].w};
      #pragma unroll
      for (int j = 0; j < 4; ++j) {
        const float w = wv[j];
        s[j]   += w;
        wx0[j] = fmaf(w, x0, wx0[j]);
        wx1[j] = fmaf(w, x1, wx1[j]);
        wx2[j] = fmaf(w, x2, wx2[j]);
        e00[j] = fmaf(w, xx00, e00[j]);
        e10[j] = fmaf(w, xx10, e10[j]);
        e11[j] = fmaf(w, xx11, e11[j]);
        e20[j] = fmaf(w, xx20, e20[j]);
        e21[j] = fmaf(w, xx21, e21[j]);
        e22[j] = fmaf(w, xx22, e22[j]);
      }
    }
  }

  // Epilogue: cov lower-tri order (0,0),(1,0),(1,1),(2,0),(2,1),(2,2) + mean.
  float cov[24];
  float mn[12];
  #pragma unroll
  for (int j = 0; j < 4; ++j) {
    const float iw = 1.0f / (s[j] + EPS);
    const float m0 = wx0[j] * iw;
    const float m1 = wx1[j] * iw;
    const float m2 = wx2[j] * iw;
    cov[j * 6 + 0] = fmaf(-m0, m0, e00[j] * iw);
    cov[j * 6 + 1] = fmaf(-m1, m0, e10[j] * iw);
    cov[j * 6 + 2] = fmaf(-m1, m1, e11[j] * iw);
    cov[j * 6 + 3] = fmaf(-m2, m0, e20[j] * iw);
    cov[j * 6 + 4] = fmaf(-m2, m1, e21[j] * iw);
    cov[j * 6 + 5] = fmaf(-m2, m2, e22[j] * iw);
    mn[j * 3 + 0] = m0;
    mn[j * 3 + 1] = m1;
    mn[j * 3 + 2] = m2;
  }

  // Normal cached float4 stores (L2 write-combines). All 16B-aligned.
  float* outv = out + (size_t)v * 144;
  v4f* cdst = reinterpret_cast<v4f*>(outv + t * 24);       // 24 floats
  const v4f* csrc = reinterpret_cast<const v4f*>(cov);
  #pragma unroll
  for (int q = 0; q < 6; ++q) cdst[q] = csrc[q];
  v4f* mdst = reinterpret_cast<v4f*>(outv + 96 + t * 12);  // 12 floats
  const v4f* msrc = reinterpret_cast<const v4f*>(mn);
  #pragma unroll
  for (int q = 0; q < 3; ++q) mdst[q] = msrc[q];
}

// ---------------------------------------------------------------------------
// Fallback (no workspace): f32 path, R1 structure.
// ---------------------------------------------------------------------------
__global__ __launch_bounds__(THREADS) void neigh_cov_f_kernel(
    const float* __restrict__ coords,
    const float* __restrict__ feats,
    const int*   __restrict__ nidx,
    float*       __restrict__ out,
    int V)
{
  __shared__ int sidx[V_PER_BLOCK][K_N + 1];
  const int tid = threadIdx.x;
  const int block_v0 = blockIdx.x * V_PER_BLOCK;
  {
    const long long base = (long long)block_v0 * K_N;
    const long long avail = (long long)V * K_N - base;
    for (int i = tid; i < V_PER_BLOCK * K_N; i += THREADS) {
      int val = (i < avail) ? nidx[base + i] : 0;
      sidx[i / K_N][i % K_N] = val;
    }
  }
  __syncthreads();
  const int vloc = tid >> 2, t = tid & 3;
  const int v = block_v0 + vloc;
  if (v >= V) return;
  float s[4] = {0,0,0,0}, wx0[4] = {0,0,0,0}, wx1[4] = {0,0,0,0}, wx2[4] = {0,0,0,0};
  float e00[4] = {0,0,0,0}, e10[4] = {0,0,0,0}, e11[4] = {0,0,0,0};
  float e20[4] = {0,0,0,0}, e21[4] = {0,0,0,0}, e22[4] = {0,0,0,0};
  #pragma unroll 4
  for (int k = 0; k < K_N; ++k) {
    const int idx = sidx[vloc][k];
    const v4f w4 = *reinterpret_cast<const v4f*>(feats + (size_t)idx * F_DIM + t * 4);
    const float x0 = coords[(size_t)idx * C_DIM + 0];
    const float x1 = coords[(size_t)idx * C_DIM + 1];
    const float x2 = coords[(size_t)idx * C_DIM + 2];
    const float xx00 = x0*x0, xx10 = x1*x0, xx11 = x1*x1;
    const float xx20 = x2*x0, xx21 = x2*x1, xx22 = x2*x2;
    const float wv[4] = {w4.x, w4.y, w4.z, w4.w};
    #pragma unroll
    for (int j = 0; j < 4; ++j) {
      const float w = wv[j];
      s[j] += w;
      wx0[j] = fmaf(w, x0, wx0[j]); wx1[j] = fmaf(w, x1, wx1[j]); wx2[j] = fmaf(w, x2, wx2[j]);
      e00[j] = fmaf(w, xx00, e00[j]); e10[j] = fmaf(w, xx10, e10[j]); e11[j] = fmaf(w, xx11, e11[j]);
      e20[j] = fmaf(w, xx20, e20[j]); e21[j] = fmaf(w, xx21, e21[j]); e22[j] = fmaf(w, xx22, e22[j]);
    }
  }
  float cov[24], mn[12];
  #pragma unroll
  for (int j = 0; j < 4; ++j) {
    const float iw = 1.0f / (s[j] + EPS);
    const float m0 = wx0[j]*iw, m1 = wx1[j]*iw, m2 = wx2[j]*iw;
    cov[j*6+0] = fmaf(-m0, m0, e00[j]*iw);
    cov[j*6+1] = fmaf(-m1, m0, e10[j]*iw);
    cov[j*6+2] = fmaf(-m1, m1, e11[j]*iw);
    cov[j*6+3] = fmaf(-m2, m0, e20[j]*iw);
    cov[j*6+4] = fmaf(-m2, m1, e21[j]*iw);
    cov[j*6+5] = fmaf(-m2, m2, e22[j]*iw);
    mn[j*3+0] = m0; mn[j*3+1] = m1; mn[j*3+2] = m2;
  }
  float* outv = out + (size_t)v * 144;
  v4f* cdst = reinterpret_cast<v4f*>(outv + t * 24);
  const v4f* csrc = reinterpret_cast<const v4f*>(cov);
  #pragma unroll
  for (int q = 0; q < 6; ++q) cdst[q] = csrc[q];
  v4f* mdst = reinterpret_cast<v4f*>(outv + 96 + t * 12);
  const v4f* msrc = reinterpret_cast<const v4f*>(mn);
  #pragma unroll
  for (int q = 0; q < 3; ++q) mdst[q] = msrc[q];
}

extern "C" void kernel_launch(void* const* d_in, const int* in_sizes, int n_in,
                              void* d_out, int out_size, void* d_ws, size_t ws_size,
                              hipStream_t stream) {
  const float* coords = (const float*)d_in[0];
  const float* feats  = (const float*)d_in[1];
  const int*   nidx   = (const int*)d_in[2];
  float* out = (float*)d_out;

  const int V = in_sizes[0] / C_DIM;   // 200000
  const int blocks = (V + V_PER_BLOCK - 1) / V_PER_BLOCK;

  const size_t fh_bytes = (size_t)V * F_DIM * sizeof(_Float16);  // 6.4 MB
  const size_t ch_bytes = (size_t)V * sizeof(h4);                // 1.6 MB
  const bool use_half = (d_ws != nullptr) && (ws_size >= fh_bytes + ch_bytes);

  if (use_half) {
    h4* fh = (h4*)d_ws;
    h4* ch = (h4*)((char*)d_ws + fh_bytes);
    pack_half_kernel<<<(V + 255) / 256, 256, 0, stream>>>(coords, feats, fh, ch, V);
    neigh_cov_h_kernel<<<blocks, THREADS, 0, stream>>>(fh, ch, nidx, out, V);
  } else {
    neigh_cov_f_kernel<<<blocks, THREADS, 0, stream>>>(coords, feats, nidx, out, V);
  }
}

// Round 6
// 122.210 us; speedup vs baseline: 2.5202x; 1.1649x over previous
//
#include <hip/hip_runtime.h>

// NeighbourCovariance: V=200000, C=3, F=16, K=32
// out[v] = [cov_flat (F*6=96), mean_flat (F*3=48)] -> 144 f32 per vertex.
//
// Ledger:
//  R3: NT stores -> 3x write amplification. BANNED.
//  R4: f32 coord packing neutral (coords already L2-resident).
//  R5: fp16 gather: FETCH 540->333 MB, 131 us. Fabric plateau ~3.5 TB/s ->
//      we are FETCH+WRITE byte-bound; feats array (6.4 MB fp16) > 4 MB L2
//      was the dominant miss stream.
//  R6: feats -> u8 fixed-point (3.2 MB, fits L2). 1/255 scale cancels in
//      mean/cov (folded into EPS); decode = v_cvt_f32_ubyte. One 16B line
//      request per vertex-neighbor for the whole feature row.

#define EPS 1e-6f

constexpr int C_DIM = 3;
constexpr int F_DIM = 16;
constexpr int K_N = 32;
constexpr int V_PER_BLOCK = 64;   // 256 threads, 4 threads/vertex
constexpr int THREADS = 256;

typedef float v4f __attribute__((ext_vector_type(4)));
typedef _Float16 h4 __attribute__((ext_vector_type(4)));   // 8B

// ---------------------------------------------------------------------------
// Prepass: feats f32[V,16] -> u8[V,16] packed as uint[V,4] (3.2 MB);
// coords f32[V,3] -> fp16x4 (x,y,z,0) [V] (1.6 MB).
// ---------------------------------------------------------------------------
__global__ __launch_bounds__(256) void pack_q_kernel(
    const float* __restrict__ coords,
    const float* __restrict__ feats,
    unsigned int* __restrict__ fq,   // [V*4] each = 4 packed u8
    h4* __restrict__ ch,             // [V]
    int V)
{
  int v = blockIdx.x * blockDim.x + threadIdx.x;
  if (v >= V) return;
  #pragma unroll
  for (int q = 0; q < 4; ++q) {
    const v4f f = *reinterpret_cast<const v4f*>(feats + (size_t)v * F_DIM + q * 4);
    unsigned int b0 = (unsigned int)__float2int_rn(fminf(fmaxf(f.x, 0.f), 1.f) * 255.f);
    unsigned int b1 = (unsigned int)__float2int_rn(fminf(fmaxf(f.y, 0.f), 1.f) * 255.f);
    unsigned int b2 = (unsigned int)__float2int_rn(fminf(fmaxf(f.z, 0.f), 1.f) * 255.f);
    unsigned int b3 = (unsigned int)__float2int_rn(fminf(fmaxf(f.w, 0.f), 1.f) * 255.f);
    fq[(size_t)v * 4 + q] = b0 | (b1 << 8) | (b2 << 16) | (b3 << 24);
  }
  h4 c;
  c.x = (_Float16)coords[(size_t)v * 3 + 0];
  c.y = (_Float16)coords[(size_t)v * 3 + 1];
  c.z = (_Float16)coords[(size_t)v * 3 + 2];
  c.w = (_Float16)0.f;
  ch[v] = c;
}

// ---------------------------------------------------------------------------
// Main kernel (u8-feature gather path). Accumulates RAW u8 counts (255*w);
// the 1/255 scale cancels in mean & cov provided EPS is scaled by 255.
// ---------------------------------------------------------------------------
__global__ __launch_bounds__(THREADS) void neigh_cov_q_kernel(
    const unsigned int* __restrict__ fq,   // [V*4]
    const h4* __restrict__ ch,             // [V]
    const int* __restrict__ nidx,          // [V,32]
    float* __restrict__ out,               // [V,144]
    int V)
{
  __shared__ int sidx[V_PER_BLOCK][K_N + 1];   // stride 33: conflict-free

  const int tid = threadIdx.x;
  const int block_v0 = blockIdx.x * V_PER_BLOCK;

  {
    const long long base = (long long)block_v0 * K_N;
    const long long avail = (long long)V * K_N - base;
    #pragma unroll
    for (int i = tid; i < V_PER_BLOCK * K_N; i += THREADS) {
      int val = (i < avail) ? __builtin_nontemporal_load(nidx + base + i) : 0;
      sidx[i / K_N][i % K_N] = val;
    }
  }
  __syncthreads();

  const int vloc = tid >> 2;   // vertex within block
  const int t    = tid & 3;    // feature quad: features 4t..4t+3
  const int v    = block_v0 + vloc;
  if (v >= V) return;

  float s[4]   = {0.f, 0.f, 0.f, 0.f};
  float wx0[4] = {0.f, 0.f, 0.f, 0.f};
  float wx1[4] = {0.f, 0.f, 0.f, 0.f};
  float wx2[4] = {0.f, 0.f, 0.f, 0.f};
  float e00[4] = {0.f, 0.f, 0.f, 0.f};
  float e10[4] = {0.f, 0.f, 0.f, 0.f};
  float e11[4] = {0.f, 0.f, 0.f, 0.f};
  float e20[4] = {0.f, 0.f, 0.f, 0.f};
  float e21[4] = {0.f, 0.f, 0.f, 0.f};
  float e22[4] = {0.f, 0.f, 0.f, 0.f};

  // Batch 8 gathers in flight (1 dword + 1 h4 per neighbor), then accumulate.
  #pragma unroll
  for (int kb = 0; kb < K_N; kb += 8) {
    unsigned int uq[8];
    h4 cc[8];
    #pragma unroll
    for (int u = 0; u < 8; ++u) {
      const int idx = sidx[vloc][kb + u];
      // 4 lanes of a vertex load consecutive dwords: one 16B line request.
      uq[u] = fq[(size_t)idx * 4 + t];
      cc[u] = ch[idx];                 // 8B broadcast, L2-resident
    }
    #pragma unroll
    for (int u = 0; u < 8; ++u) {
      const float x0 = (float)cc[u].x;
      const float x1 = (float)cc[u].y;
      const float x2 = (float)cc[u].z;
      const float xx00 = x0 * x0;
      const float xx10 = x1 * x0;
      const float xx11 = x1 * x1;
      const float xx20 = x2 * x0;
      const float xx21 = x2 * x1;
      const float xx22 = x2 * x2;
      // v_cvt_f32_ubyte0..3
      const unsigned int q = uq[u];
      const float wv[4] = {(float)(q & 0xffu), (float)((q >> 8) & 0xffu),
                           (float)((q >> 16) & 0xffu), (float)(q >> 24)};
      #pragma unroll
      for (int j = 0; j < 4; ++j) {
        const float w = wv[j];
        s[j]   += w;
        wx0[j] = fmaf(w, x0, wx0[j]);
        wx1[j] = fmaf(w, x1, wx1[j]);
        wx2[j] = fmaf(w, x2, wx2[j]);
        e00[j] = fmaf(w, xx00, e00[j]);
        e10[j] = fmaf(w, xx10, e10[j]);
        e11[j] = fmaf(w, xx11, e11[j]);
        e20[j] = fmaf(w, xx20, e20[j]);
        e21[j] = fmaf(w, xx21, e21[j]);
        e22[j] = fmaf(w, xx22, e22[j]);
      }
    }
  }

  // Epilogue. Raw counts: s = 255*wsum, wx = 255*Sum(w x), e = 255*Sum(w xx).
  // iw = 1/(s + 255*EPS) = (1/255) * 1/(wsum + EPS)  ->  scale cancels.
  float cov[24];
  float mn[12];
  #pragma unroll
  for (int j = 0; j < 4; ++j) {
    const float iw = 1.0f / (s[j] + 255.0f * EPS);
    const float m0 = wx0[j] * iw;
    const float m1 = wx1[j] * iw;
    const float m2 = wx2[j] * iw;
    cov[j * 6 + 0] = fmaf(-m0, m0, e00[j] * iw);
    cov[j * 6 + 1] = fmaf(-m1, m0, e10[j] * iw);
    cov[j * 6 + 2] = fmaf(-m1, m1, e11[j] * iw);
    cov[j * 6 + 3] = fmaf(-m2, m0, e20[j] * iw);
    cov[j * 6 + 4] = fmaf(-m2, m1, e21[j] * iw);
    cov[j * 6 + 5] = fmaf(-m2, m2, e22[j] * iw);
    mn[j * 3 + 0] = m0;
    mn[j * 3 + 1] = m1;
    mn[j * 3 + 2] = m2;
  }

  // Normal cached float4 stores (L2 write-combines). All 16B-aligned.
  float* outv = out + (size_t)v * 144;
  v4f* cdst = reinterpret_cast<v4f*>(outv + t * 24);       // 24 floats
  const v4f* csrc = reinterpret_cast<const v4f*>(cov);
  #pragma unroll
  for (int q = 0; q < 6; ++q) cdst[q] = csrc[q];
  v4f* mdst = reinterpret_cast<v4f*>(outv + 96 + t * 12);  // 12 floats
  const v4f* msrc = reinterpret_cast<const v4f*>(mn);
  #pragma unroll
  for (int q = 0; q < 3; ++q) mdst[q] = msrc[q];
}

// ---------------------------------------------------------------------------
// Fallback (no workspace): f32 path, R1 structure.
// ---------------------------------------------------------------------------
__global__ __launch_bounds__(THREADS) void neigh_cov_f_kernel(
    const float* __restrict__ coords,
    const float* __restrict__ feats,
    const int*   __restrict__ nidx,
    float*       __restrict__ out,
    int V)
{
  __shared__ int sidx[V_PER_BLOCK][K_N + 1];
  const int tid = threadIdx.x;
  const int block_v0 = blockIdx.x * V_PER_BLOCK;
  {
    const long long base = (long long)block_v0 * K_N;
    const long long avail = (long long)V * K_N - base;
    for (int i = tid; i < V_PER_BLOCK * K_N; i += THREADS) {
      int val = (i < avail) ? nidx[base + i] : 0;
      sidx[i / K_N][i % K_N] = val;
    }
  }
  __syncthreads();
  const int vloc = tid >> 2, t = tid & 3;
  const int v = block_v0 + vloc;
  if (v >= V) return;
  float s[4] = {0,0,0,0}, wx0[4] = {0,0,0,0}, wx1[4] = {0,0,0,0}, wx2[4] = {0,0,0,0};
  float e00[4] = {0,0,0,0}, e10[4] = {0,0,0,0}, e11[4] = {0,0,0,0};
  float e20[4] = {0,0,0,0}, e21[4] = {0,0,0,0}, e22[4] = {0,0,0,0};
  #pragma unroll 4
  for (int k = 0; k < K_N; ++k) {
    const int idx = sidx[vloc][k];
    const v4f w4 = *reinterpret_cast<const v4f*>(feats + (size_t)idx * F_DIM + t * 4);
    const float x0 = coords[(size_t)idx * C_DIM + 0];
    const float x1 = coords[(size_t)idx * C_DIM + 1];
    const float x2 = coords[(size_t)idx * C_DIM + 2];
    const float xx00 = x0*x0, xx10 = x1*x0, xx11 = x1*x1;
    const float xx20 = x2*x0, xx21 = x2*x1, xx22 = x2*x2;
    const float wv[4] = {w4.x, w4.y, w4.z, w4.w};
    #pragma unroll
    for (int j = 0; j < 4; ++j) {
      const float w = wv[j];
      s[j] += w;
      wx0[j] = fmaf(w, x0, wx0[j]); wx1[j] = fmaf(w, x1, wx1[j]); wx2[j] = fmaf(w, x2, wx2[j]);
      e00[j] = fmaf(w, xx00, e00[j]); e10[j] = fmaf(w, xx10, e10[j]); e11[j] = fmaf(w, xx11, e11[j]);
      e20[j] = fmaf(w, xx20, e20[j]); e21[j] = fmaf(w, xx21, e21[j]); e22[j] = fmaf(w, xx22, e22[j]);
    }
  }
  float cov[24], mn[12];
  #pragma unroll
  for (int j = 0; j < 4; ++j) {
    const float iw = 1.0f / (s[j] + EPS);
    const float m0 = wx0[j]*iw, m1 = wx1[j]*iw, m2 = wx2[j]*iw;
    cov[j*6+0] = fmaf(-m0, m0, e00[j]*iw);
    cov[j*6+1] = fmaf(-m1, m0, e10[j]*iw);
    cov[j*6+2] = fmaf(-m1, m1, e11[j]*iw);
    cov[j*6+3] = fmaf(-m2, m0, e20[j]*iw);
    cov[j*6+4] = fmaf(-m2, m1, e21[j]*iw);
    cov[j*6+5] = fmaf(-m2, m2, e22[j]*iw);
    mn[j*3+0] = m0; mn[j*3+1] = m1; mn[j*3+2] = m2;
  }
  float* outv = out + (size_t)v * 144;
  v4f* cdst = reinterpret_cast<v4f*>(outv + t * 24);
  const v4f* csrc = reinterpret_cast<const v4f*>(cov);
  #pragma unroll
  for (int q = 0; q < 6; ++q) cdst[q] = csrc[q];
  v4f* mdst = reinterpret_cast<v4f*>(outv + 96 + t * 12);
  const v4f* msrc = reinterpret_cast<const v4f*>(mn);
  #pragma unroll
  for (int q = 0; q < 3; ++q) mdst[q] = msrc[q];
}

extern "C" void kernel_launch(void* const* d_in, const int* in_sizes, int n_in,
                              void* d_out, int out_size, void* d_ws, size_t ws_size,
                              hipStream_t stream) {
  const float* coords = (const float*)d_in[0];
  const float* feats  = (const float*)d_in[1];
  const int*   nidx   = (const int*)d_in[2];
  float* out = (float*)d_out;

  const int V = in_sizes[0] / C_DIM;   // 200000
  const int blocks = (V + V_PER_BLOCK - 1) / V_PER_BLOCK;

  const size_t fq_bytes = (size_t)V * 4 * sizeof(unsigned int);  // 3.2 MB
  const size_t ch_bytes = (size_t)V * sizeof(h4);                // 1.6 MB
  const bool use_q = (d_ws != nullptr) && (ws_size >= fq_bytes + ch_bytes);

  if (use_q) {
    unsigned int* fq = (unsigned int*)d_ws;
    h4* ch = (h4*)((char*)d_ws + fq_bytes);
    pack_q_kernel<<<(V + 255) / 256, 256, 0, stream>>>(coords, feats, fq, ch, V);
    neigh_cov_q_kernel<<<blocks, THREADS, 0, stream>>>(fq, ch, nidx, out, V);
  } else {
    neigh_cov_f_kernel<<<blocks, THREADS, 0, stream>>>(coords, feats, nidx, out, V);
  }
}

// Round 7
// 104.814 us; speedup vs baseline: 2.9384x; 1.1660x over previous
//
#include <hip/hip_runtime.h>

// NeighbourCovariance: V=200000, C=3, F=16, K=32
// out[v] = [cov_flat (F*6=96), mean_flat (F*3=48)] -> 144 f32 per vertex.
//
// Ledger:
//  R3: NT stores -> 3x write amplification. BANNED.
//  R4: f32 coord packing neutral (coords already L2-resident); extra VGPRs
//      cost occupancy.
//  R5: fp16 gather: FETCH 540->333 MB, 131 us.
//  R6: u8 feats (scale cancels in mean/cov): FETCH 333->186 MB, 115 us.
//      Sub-linear time gain -> line-touch/request cost surfacing.
//  R7: fuse feats+coords into ONE 24B record (16B u8 feats + 6B fp16 coords
//      + 2B pad): 1.25 lines/neighbor avg instead of 2.0, same 4.8 MB
//      footprint, same instruction count.

#define EPS 1e-6f

constexpr int C_DIM = 3;
constexpr int F_DIM = 16;
constexpr int K_N = 32;
constexpr int V_PER_BLOCK = 64;   // 256 threads, 4 threads/vertex
constexpr int THREADS = 256;

typedef float v4f __attribute__((ext_vector_type(4)));
typedef _Float16 h4 __attribute__((ext_vector_type(4)));   // 8B
typedef unsigned int u32;

// Record: dwords [0..3] = 16 u8 feats, dwords [4..5] = fp16 x,y,z + pad.
// Stride 6 dwords = 24B; base 8B-aligned for every v (24 % 8 == 0).

// ---------------------------------------------------------------------------
// Prepass: build rec[V] from f32 inputs.
// ---------------------------------------------------------------------------
__global__ __launch_bounds__(256) void pack_rec_kernel(
    const float* __restrict__ coords,
    const float* __restrict__ feats,
    u32* __restrict__ rec,
    int V)
{
  int v = blockIdx.x * blockDim.x + threadIdx.x;
  if (v >= V) return;

  u32 r[6];
  #pragma unroll
  for (int q = 0; q < 4; ++q) {
    const v4f f = *reinterpret_cast<const v4f*>(feats + (size_t)v * F_DIM + q * 4);
    u32 b0 = (u32)__float2int_rn(fminf(fmaxf(f.x, 0.f), 1.f) * 255.f);
    u32 b1 = (u32)__float2int_rn(fminf(fmaxf(f.y, 0.f), 1.f) * 255.f);
    u32 b2 = (u32)__float2int_rn(fminf(fmaxf(f.z, 0.f), 1.f) * 255.f);
    u32 b3 = (u32)__float2int_rn(fminf(fmaxf(f.w, 0.f), 1.f) * 255.f);
    r[q] = b0 | (b1 << 8) | (b2 << 16) | (b3 << 24);
  }
  h4 c;
  c.x = (_Float16)coords[(size_t)v * 3 + 0];
  c.y = (_Float16)coords[(size_t)v * 3 + 1];
  c.z = (_Float16)coords[(size_t)v * 3 + 2];
  c.w = (_Float16)0.f;
  const u32* cw = reinterpret_cast<const u32*>(&c);
  r[4] = cw[0];
  r[5] = cw[1];

  u32* dst = rec + (size_t)v * 6;
  // 3x 8B stores (8B-aligned).
  *reinterpret_cast<uint2*>(dst + 0) = make_uint2(r[0], r[1]);
  *reinterpret_cast<uint2*>(dst + 2) = make_uint2(r[2], r[3]);
  *reinterpret_cast<uint2*>(dst + 4) = make_uint2(r[4], r[5]);
}

// ---------------------------------------------------------------------------
// Main kernel (fused-record gather). Accumulates RAW u8 counts (255*w);
// the 1/255 scale cancels in mean & cov with EPS scaled by 255.
// ---------------------------------------------------------------------------
__global__ __launch_bounds__(THREADS) void neigh_cov_r_kernel(
    const u32* __restrict__ rec,    // [V*6]
    const int* __restrict__ nidx,   // [V,32]
    float* __restrict__ out,        // [V,144]
    int V)
{
  __shared__ int sidx[V_PER_BLOCK][K_N + 1];   // stride 33: conflict-free

  const int tid = threadIdx.x;
  const int block_v0 = blockIdx.x * V_PER_BLOCK;

  {
    const long long base = (long long)block_v0 * K_N;
    const long long avail = (long long)V * K_N - base;
    #pragma unroll
    for (int i = tid; i < V_PER_BLOCK * K_N; i += THREADS) {
      int val = (i < avail) ? __builtin_nontemporal_load(nidx + base + i) : 0;
      sidx[i / K_N][i % K_N] = val;
    }
  }
  __syncthreads();

  const int vloc = tid >> 2;   // vertex within block
  const int t    = tid & 3;    // feature quad: features 4t..4t+3
  const int v    = block_v0 + vloc;
  if (v >= V) return;

  float s[4]   = {0.f, 0.f, 0.f, 0.f};
  float wx0[4] = {0.f, 0.f, 0.f, 0.f};
  float wx1[4] = {0.f, 0.f, 0.f, 0.f};
  float wx2[4] = {0.f, 0.f, 0.f, 0.f};
  float e00[4] = {0.f, 0.f, 0.f, 0.f};
  float e10[4] = {0.f, 0.f, 0.f, 0.f};
  float e11[4] = {0.f, 0.f, 0.f, 0.f};
  float e20[4] = {0.f, 0.f, 0.f, 0.f};
  float e21[4] = {0.f, 0.f, 0.f, 0.f};
  float e22[4] = {0.f, 0.f, 0.f, 0.f};

  // Batch 8 gathers in flight (1 dword + 1 8B load per neighbor, usually
  // the SAME cache line), then accumulate.
  #pragma unroll
  for (int kb = 0; kb < K_N; kb += 8) {
    u32 uq[8];
    h4 cc[8];
    #pragma unroll
    for (int u = 0; u < 8; ++u) {
      const int idx = sidx[vloc][kb + u];
      const u32* rp = rec + (size_t)idx * 6;
      uq[u] = rp[t];                                  // feature word (lane t)
      cc[u] = *reinterpret_cast<const h4*>(rp + 4);   // coords, 8B-aligned
    }
    #pragma unroll
    for (int u = 0; u < 8; ++u) {
      const float x0 = (float)cc[u].x;
      const float x1 = (float)cc[u].y;
      const float x2 = (float)cc[u].z;
      const float xx00 = x0 * x0;
      const float xx10 = x1 * x0;
      const float xx11 = x1 * x1;
      const float xx20 = x2 * x0;
      const float xx21 = x2 * x1;
      const float xx22 = x2 * x2;
      const u32 q = uq[u];
      // v_cvt_f32_ubyte0..3
      const float wv[4] = {(float)(q & 0xffu), (float)((q >> 8) & 0xffu),
                           (float)((q >> 16) & 0xffu), (float)(q >> 24)};
      #pragma unroll
      for (int j = 0; j < 4; ++j) {
        const float w = wv[j];
        s[j]   += w;
        wx0[j] = fmaf(w, x0, wx0[j]);
        wx1[j] = fmaf(w, x1, wx1[j]);
        wx2[j] = fmaf(w, x2, wx2[j]);
        e00[j] = fmaf(w, xx00, e00[j]);
        e10[j] = fmaf(w, xx10, e10[j]);
        e11[j] = fmaf(w, xx11, e11[j]);
        e20[j] = fmaf(w, xx20, e20[j]);
        e21[j] = fmaf(w, xx21, e21[j]);
        e22[j] = fmaf(w, xx22, e22[j]);
      }
    }
  }

  // Epilogue. Raw counts: s = 255*wsum; iw scale cancels with EPS*255.
  float cov[24];
  float mn[12];
  #pragma unroll
  for (int j = 0; j < 4; ++j) {
    const float iw = 1.0f / (s[j] + 255.0f * EPS);
    const float m0 = wx0[j] * iw;
    const float m1 = wx1[j] * iw;
    const float m2 = wx2[j] * iw;
    cov[j * 6 + 0] = fmaf(-m0, m0, e00[j] * iw);
    cov[j * 6 + 1] = fmaf(-m1, m0, e10[j] * iw);
    cov[j * 6 + 2] = fmaf(-m1, m1, e11[j] * iw);
    cov[j * 6 + 3] = fmaf(-m2, m0, e20[j] * iw);
    cov[j * 6 + 4] = fmaf(-m2, m1, e21[j] * iw);
    cov[j * 6 + 5] = fmaf(-m2, m2, e22[j] * iw);
    mn[j * 3 + 0] = m0;
    mn[j * 3 + 1] = m1;
    mn[j * 3 + 2] = m2;
  }

  // Normal cached float4 stores (L2 write-combines). All 16B-aligned.
  float* outv = out + (size_t)v * 144;
  v4f* cdst = reinterpret_cast<v4f*>(outv + t * 24);       // 24 floats
  const v4f* csrc = reinterpret_cast<const v4f*>(cov);
  #pragma unroll
  for (int q = 0; q < 6; ++q) cdst[q] = csrc[q];
  v4f* mdst = reinterpret_cast<v4f*>(outv + 96 + t * 12);  // 12 floats
  const v4f* msrc = reinterpret_cast<const v4f*>(mn);
  #pragma unroll
  for (int q = 0; q < 3; ++q) mdst[q] = msrc[q];
}

// ---------------------------------------------------------------------------
// Fallback (no workspace): f32 path, R1 structure.
// ---------------------------------------------------------------------------
__global__ __launch_bounds__(THREADS) void neigh_cov_f_kernel(
    const float* __restrict__ coords,
    const float* __restrict__ feats,
    const int*   __restrict__ nidx,
    float*       __restrict__ out,
    int V)
{
  __shared__ int sidx[V_PER_BLOCK][K_N + 1];
  const int tid = threadIdx.x;
  const int block_v0 = blockIdx.x * V_PER_BLOCK;
  {
    const long long base = (long long)block_v0 * K_N;
    const long long avail = (long long)V * K_N - base;
    for (int i = tid; i < V_PER_BLOCK * K_N; i += THREADS) {
      int val = (i < avail) ? nidx[base + i] : 0;
      sidx[i / K_N][i % K_N] = val;
    }
  }
  __syncthreads();
  const int vloc = tid >> 2, t = tid & 3;
  const int v = block_v0 + vloc;
  if (v >= V) return;
  float s[4] = {0,0,0,0}, wx0[4] = {0,0,0,0}, wx1[4] = {0,0,0,0}, wx2[4] = {0,0,0,0};
  float e00[4] = {0,0,0,0}, e10[4] = {0,0,0,0}, e11[4] = {0,0,0,0};
  float e20[4] = {0,0,0,0}, e21[4] = {0,0,0,0}, e22[4] = {0,0,0,0};
  #pragma unroll 4
  for (int k = 0; k < K_N; ++k) {
    const int idx = sidx[vloc][k];
    const v4f w4 = *reinterpret_cast<const v4f*>(feats + (size_t)idx * F_DIM + t * 4);
    const float x0 = coords[(size_t)idx * C_DIM + 0];
    const float x1 = coords[(size_t)idx * C_DIM + 1];
    const float x2 = coords[(size_t)idx * C_DIM + 2];
    const float xx00 = x0*x0, xx10 = x1*x0, xx11 = x1*x1;
    const float xx20 = x2*x0, xx21 = x2*x1, xx22 = x2*x2;
    const float wv[4] = {w4.x, w4.y, w4.z, w4.w};
    #pragma unroll
    for (int j = 0; j < 4; ++j) {
      const float w = wv[j];
      s[j] += w;
      wx0[j] = fmaf(w, x0, wx0[j]); wx1[j] = fmaf(w, x1, wx1[j]); wx2[j] = fmaf(w, x2, wx2[j]);
      e00[j] = fmaf(w, xx00, e00[j]); e10[j] = fmaf(w, xx10, e10[j]); e11[j] = fmaf(w, xx11, e11[j]);
      e20[j] = fmaf(w, xx20, e20[j]); e21[j] = fmaf(w, xx21, e21[j]); e22[j] = fmaf(w, xx22, e22[j]);
    }
  }
  float cov[24], mn[12];
  #pragma unroll
  for (int j = 0; j < 4; ++j) {
    const float iw = 1.0f / (s[j] + EPS);
    const float m0 = wx0[j]*iw, m1 = wx1[j]*iw, m2 = wx2[j]*iw;
    cov[j*6+0] = fmaf(-m0, m0, e00[j]*iw);
    cov[j*6+1] = fmaf(-m1, m0, e10[j]*iw);
    cov[j*6+2] = fmaf(-m1, m1, e11[j]*iw);
    cov[j*6+3] = fmaf(-m2, m0, e20[j]*iw);
    cov[j*6+4] = fmaf(-m2, m1, e21[j]*iw);
    cov[j*6+5] = fmaf(-m2, m2, e22[j]*iw);
    mn[j*3+0] = m0; mn[j*3+1] = m1; mn[j*3+2] = m2;
  }
  float* outv = out + (size_t)v * 144;
  v4f* cdst = reinterpret_cast<v4f*>(outv + t * 24);
  const v4f* csrc = reinterpret_cast<const v4f*>(cov);
  #pragma unroll
  for (int q = 0; q < 6; ++q) cdst[q] = csrc[q];
  v4f* mdst = reinterpret_cast<v4f*>(outv + 96 + t * 12);
  const v4f* msrc = reinterpret_cast<const v4f*>(mn);
  #pragma unroll
  for (int q = 0; q < 3; ++q) mdst[q] = msrc[q];
}

extern "C" void kernel_launch(void* const* d_in, const int* in_sizes, int n_in,
                              void* d_out, int out_size, void* d_ws, size_t ws_size,
                              hipStream_t stream) {
  const float* coords = (const float*)d_in[0];
  const float* feats  = (const float*)d_in[1];
  const int*   nidx   = (const int*)d_in[2];
  float* out = (float*)d_out;

  const int V = in_sizes[0] / C_DIM;   // 200000
  const int blocks = (V + V_PER_BLOCK - 1) / V_PER_BLOCK;

  const size_t rec_bytes = (size_t)V * 24;   // 4.8 MB
  const bool use_rec = (d_ws != nullptr) && (ws_size >= rec_bytes);

  if (use_rec) {
    u32* rec = (u32*)d_ws;
    pack_rec_kernel<<<(V + 255) / 256, 256, 0, stream>>>(coords, feats, rec, V);
    neigh_cov_r_kernel<<<blocks, THREADS, 0, stream>>>(rec, nidx, out, V);
  } else {
    neigh_cov_f_kernel<<<blocks, THREADS, 0, stream>>>(coords, feats, nidx, out, V);
  }
}

// Round 8
// 104.725 us; speedup vs baseline: 2.9409x; 1.0009x over previous
//
#include <hip/hip_runtime.h>

// NeighbourCovariance: V=200000, C=3, F=16, K=32
// out[v] = [cov_flat (F*6=96), mean_flat (F*3=48)] -> 144 f32 per vertex.
//
// Ledger:
//  R3: NT stores -> 3x write amplification. BANNED.
//  R4: f32 coord packing neutral (coords L2-resident); VGPRs cost occupancy.
//  R5: fp16 gather: FETCH 540->333 MB, 131 us.
//  R6: u8 feats (scale cancels in mean/cov): FETCH 333->186 MB, 115 us.
//  R7: fused 24B record (16B u8 feats + 6B fp16 coords + pad): FETCH
//      186->147 MB, 98 us. ~121 MB = record misses (4.8MB table vs 4MB L2).
//      No pipe saturated (VALU 30%, occ 44%, 2.7 TB/s) -> byte vs latency?
//  R8: MLP diagnostic: batch 16 gathers in flight (was 8). If latency-bound
//      -> ~80-85 us; if byte-bound -> flat.

#define EPS 1e-6f

constexpr int C_DIM = 3;
constexpr int F_DIM = 16;
constexpr int K_N = 32;
constexpr int V_PER_BLOCK = 64;   // 256 threads, 4 threads/vertex
constexpr int THREADS = 256;
constexpr int BATCH = 16;         // gathers in flight per thread

typedef float v4f __attribute__((ext_vector_type(4)));
typedef _Float16 h4 __attribute__((ext_vector_type(4)));   // 8B
typedef unsigned int u32;

// Record: dwords [0..3] = 16 u8 feats, dwords [4..5] = fp16 x,y,z + pad.
// Stride 6 dwords = 24B; 8B-aligned for every v.

// ---------------------------------------------------------------------------
// Prepass: build rec[V] from f32 inputs.
// ---------------------------------------------------------------------------
__global__ __launch_bounds__(256) void pack_rec_kernel(
    const float* __restrict__ coords,
    const float* __restrict__ feats,
    u32* __restrict__ rec,
    int V)
{
  int v = blockIdx.x * blockDim.x + threadIdx.x;
  if (v >= V) return;

  u32 r[6];
  #pragma unroll
  for (int q = 0; q < 4; ++q) {
    const v4f f = *reinterpret_cast<const v4f*>(feats + (size_t)v * F_DIM + q * 4);
    u32 b0 = (u32)__float2int_rn(fminf(fmaxf(f.x, 0.f), 1.f) * 255.f);
    u32 b1 = (u32)__float2int_rn(fminf(fmaxf(f.y, 0.f), 1.f) * 255.f);
    u32 b2 = (u32)__float2int_rn(fminf(fmaxf(f.z, 0.f), 1.f) * 255.f);
    u32 b3 = (u32)__float2int_rn(fminf(fmaxf(f.w, 0.f), 1.f) * 255.f);
    r[q] = b0 | (b1 << 8) | (b2 << 16) | (b3 << 24);
  }
  h4 c;
  c.x = (_Float16)coords[(size_t)v * 3 + 0];
  c.y = (_Float16)coords[(size_t)v * 3 + 1];
  c.z = (_Float16)coords[(size_t)v * 3 + 2];
  c.w = (_Float16)0.f;
  const u32* cw = reinterpret_cast<const u32*>(&c);
  r[4] = cw[0];
  r[5] = cw[1];

  u32* dst = rec + (size_t)v * 6;
  *reinterpret_cast<uint2*>(dst + 0) = make_uint2(r[0], r[1]);
  *reinterpret_cast<uint2*>(dst + 2) = make_uint2(r[2], r[3]);
  *reinterpret_cast<uint2*>(dst + 4) = make_uint2(r[4], r[5]);
}

// ---------------------------------------------------------------------------
// Main kernel (fused-record gather, 16 gathers in flight).
// ---------------------------------------------------------------------------
__global__ __launch_bounds__(THREADS) void neigh_cov_r_kernel(
    const u32* __restrict__ rec,    // [V*6]
    const int* __restrict__ nidx,   // [V,32]
    float* __restrict__ out,        // [V,144]
    int V)
{
  __shared__ int sidx[V_PER_BLOCK][K_N + 1];   // stride 33: conflict-free

  const int tid = threadIdx.x;
  const int block_v0 = blockIdx.x * V_PER_BLOCK;

  {
    const long long base = (long long)block_v0 * K_N;
    const long long avail = (long long)V * K_N - base;
    #pragma unroll
    for (int i = tid; i < V_PER_BLOCK * K_N; i += THREADS) {
      int val = (i < avail) ? __builtin_nontemporal_load(nidx + base + i) : 0;
      sidx[i / K_N][i % K_N] = val;
    }
  }
  __syncthreads();

  const int vloc = tid >> 2;   // vertex within block
  const int t    = tid & 3;    // feature quad: features 4t..4t+3
  const int v    = block_v0 + vloc;
  if (v >= V) return;

  float s[4]   = {0.f, 0.f, 0.f, 0.f};
  float wx0[4] = {0.f, 0.f, 0.f, 0.f};
  float wx1[4] = {0.f, 0.f, 0.f, 0.f};
  float wx2[4] = {0.f, 0.f, 0.f, 0.f};
  float e00[4] = {0.f, 0.f, 0.f, 0.f};
  float e10[4] = {0.f, 0.f, 0.f, 0.f};
  float e11[4] = {0.f, 0.f, 0.f, 0.f};
  float e20[4] = {0.f, 0.f, 0.f, 0.f};
  float e21[4] = {0.f, 0.f, 0.f, 0.f};
  float e22[4] = {0.f, 0.f, 0.f, 0.f};

  #pragma unroll
  for (int kb = 0; kb < K_N; kb += BATCH) {
    u32 uq[BATCH];
    h4 cc[BATCH];
    #pragma unroll
    for (int u = 0; u < BATCH; ++u) {
      const int idx = sidx[vloc][kb + u];
      const u32* rp = rec + (size_t)idx * 6;
      uq[u] = rp[t];                                  // feature word (lane t)
      cc[u] = *reinterpret_cast<const h4*>(rp + 4);   // coords, 8B-aligned
    }
    #pragma unroll
    for (int u = 0; u < BATCH; ++u) {
      const float x0 = (float)cc[u].x;
      const float x1 = (float)cc[u].y;
      const float x2 = (float)cc[u].z;
      const float xx00 = x0 * x0;
      const float xx10 = x1 * x0;
      const float xx11 = x1 * x1;
      const float xx20 = x2 * x0;
      const float xx21 = x2 * x1;
      const float xx22 = x2 * x2;
      const u32 q = uq[u];
      // v_cvt_f32_ubyte0..3
      const float wv[4] = {(float)(q & 0xffu), (float)((q >> 8) & 0xffu),
                           (float)((q >> 16) & 0xffu), (float)(q >> 24)};
      #pragma unroll
      for (int j = 0; j < 4; ++j) {
        const float w = wv[j];
        s[j]   += w;
        wx0[j] = fmaf(w, x0, wx0[j]);
        wx1[j] = fmaf(w, x1, wx1[j]);
        wx2[j] = fmaf(w, x2, wx2[j]);
        e00[j] = fmaf(w, xx00, e00[j]);
        e10[j] = fmaf(w, xx10, e10[j]);
        e11[j] = fmaf(w, xx11, e11[j]);
        e20[j] = fmaf(w, xx20, e20[j]);
        e21[j] = fmaf(w, xx21, e21[j]);
        e22[j] = fmaf(w, xx22, e22[j]);
      }
    }
  }

  // Epilogue. Raw counts: s = 255*wsum; iw scale cancels with EPS*255.
  float cov[24];
  float mn[12];
  #pragma unroll
  for (int j = 0; j < 4; ++j) {
    const float iw = 1.0f / (s[j] + 255.0f * EPS);
    const float m0 = wx0[j] * iw;
    const float m1 = wx1[j] * iw;
    const float m2 = wx2[j] * iw;
    cov[j * 6 + 0] = fmaf(-m0, m0, e00[j] * iw);
    cov[j * 6 + 1] = fmaf(-m1, m0, e10[j] * iw);
    cov[j * 6 + 2] = fmaf(-m1, m1, e11[j] * iw);
    cov[j * 6 + 3] = fmaf(-m2, m0, e20[j] * iw);
    cov[j * 6 + 4] = fmaf(-m2, m1, e21[j] * iw);
    cov[j * 6 + 5] = fmaf(-m2, m2, e22[j] * iw);
    mn[j * 3 + 0] = m0;
    mn[j * 3 + 1] = m1;
    mn[j * 3 + 2] = m2;
  }

  // Normal cached float4 stores (L2 write-combines). All 16B-aligned.
  float* outv = out + (size_t)v * 144;
  v4f* cdst = reinterpret_cast<v4f*>(outv + t * 24);       // 24 floats
  const v4f* csrc = reinterpret_cast<const v4f*>(cov);
  #pragma unroll
  for (int q = 0; q < 6; ++q) cdst[q] = csrc[q];
  v4f* mdst = reinterpret_cast<v4f*>(outv + 96 + t * 12);  // 12 floats
  const v4f* msrc = reinterpret_cast<const v4f*>(mn);
  #pragma unroll
  for (int q = 0; q < 3; ++q) mdst[q] = msrc[q];
}

// ---------------------------------------------------------------------------
// Fallback (no workspace): f32 path, R1 structure.
// ---------------------------------------------------------------------------
__global__ __launch_bounds__(THREADS) void neigh_cov_f_kernel(
    const float* __restrict__ coords,
    const float* __restrict__ feats,
    const int*   __restrict__ nidx,
    float*       __restrict__ out,
    int V)
{
  __shared__ int sidx[V_PER_BLOCK][K_N + 1];
  const int tid = threadIdx.x;
  const int block_v0 = blockIdx.x * V_PER_BLOCK;
  {
    const long long base = (long long)block_v0 * K_N;
    const long long avail = (long long)V * K_N - base;
    for (int i = tid; i < V_PER_BLOCK * K_N; i += THREADS) {
      int val = (i < avail) ? nidx[base + i] : 0;
      sidx[i / K_N][i % K_N] = val;
    }
  }
  __syncthreads();
  const int vloc = tid >> 2, t = tid & 3;
  const int v = block_v0 + vloc;
  if (v >= V) return;
  float s[4] = {0,0,0,0}, wx0[4] = {0,0,0,0}, wx1[4] = {0,0,0,0}, wx2[4] = {0,0,0,0};
  float e00[4] = {0,0,0,0}, e10[4] = {0,0,0,0}, e11[4] = {0,0,0,0};
  float e20[4] = {0,0,0,0}, e21[4] = {0,0,0,0}, e22[4] = {0,0,0,0};
  #pragma unroll 4
  for (int k = 0; k < K_N; ++k) {
    const int idx = sidx[vloc][k];
    const v4f w4 = *reinterpret_cast<const v4f*>(feats + (size_t)idx * F_DIM + t * 4);
    const float x0 = coords[(size_t)idx * C_DIM + 0];
    const float x1 = coords[(size_t)idx * C_DIM + 1];
    const float x2 = coords[(size_t)idx * C_DIM + 2];
    const float xx00 = x0*x0, xx10 = x1*x0, xx11 = x1*x1;
    const float xx20 = x2*x0, xx21 = x2*x1, xx22 = x2*x2;
    const float wv[4] = {w4.x, w4.y, w4.z, w4.w};
    #pragma unroll
    for (int j = 0; j < 4; ++j) {
      const float w = wv[j];
      s[j] += w;
      wx0[j] = fmaf(w, x0, wx0[j]); wx1[j] = fmaf(w, x1, wx1[j]); wx2[j] = fmaf(w, x2, wx2[j]);
      e00[j] = fmaf(w, xx00, e00[j]); e10[j] = fmaf(w, xx10, e10[j]); e11[j] = fmaf(w, xx11, e11[j]);
      e20[j] = fmaf(w, xx20, e20[j]); e21[j] = fmaf(w, xx21, e21[j]); e22[j] = fmaf(w, xx22, e22[j]);
    }
  }
  float cov[24], mn[12];
  #pragma unroll
  for (int j = 0; j < 4; ++j) {
    const float iw = 1.0f / (s[j] + EPS);
    const float m0 = wx0[j]*iw, m1 = wx1[j]*iw, m2 = wx2[j]*iw;
    cov[j*6+0] = fmaf(-m0, m0, e00[j]*iw);
    cov[j*6+1] = fmaf(-m1, m0, e10[j]*iw);
    cov[j*6+2] = fmaf(-m1, m1, e11[j]*iw);
    cov[j*6+3] = fmaf(-m2, m0, e20[j]*iw);
    cov[j*6+4] = fmaf(-m2, m1, e21[j]*iw);
    cov[j*6+5] = fmaf(-m2, m2, e22[j]*iw);
    mn[j*3+0] = m0; mn[j*3+1] = m1; mn[j*3+2] = m2;
  }
  float* outv = out + (size_t)v * 144;
  v4f* cdst = reinterpret_cast<v4f*>(outv + t * 24);
  const v4f* csrc = reinterpret_cast<const v4f*>(cov);
  #pragma unroll
  for (int q = 0; q < 6; ++q) cdst[q] = csrc[q];
  v4f* mdst = reinterpret_cast<v4f*>(outv + 96 + t * 12);
  const v4f* msrc = reinterpret_cast<const v4f*>(mn);
  #pragma unroll
  for (int q = 0; q < 3; ++q) mdst[q] = msrc[q];
}

extern "C" void kernel_launch(void* const* d_in, const int* in_sizes, int n_in,
                              void* d_out, int out_size, void* d_ws, size_t ws_size,
                              hipStream_t stream) {
  const float* coords = (const float*)d_in[0];
  const float* feats  = (const float*)d_in[1];
  const int*   nidx   = (const int*)d_in[2];
  float* out = (float*)d_out;

  const int V = in_sizes[0] / C_DIM;   // 200000
  const int blocks = (V + V_PER_BLOCK - 1) / V_PER_BLOCK;

  const size_t rec_bytes = (size_t)V * 24;   // 4.8 MB
  const bool use_rec = (d_ws != nullptr) && (ws_size >= rec_bytes);

  if (use_rec) {
    u32* rec = (u32*)d_ws;
    pack_rec_kernel<<<(V + 255) / 256, 256, 0, stream>>>(coords, feats, rec, V);
    neigh_cov_r_kernel<<<blocks, THREADS, 0, stream>>>(rec, nidx, out, V);
  } else {
    neigh_cov_f_kernel<<<blocks, THREADS, 0, stream>>>(coords, feats, nidx, out, V);
  }
}